// Round 3
// baseline (470.593 us; speedup 1.0000x reference)
//
#include <hip/hip_runtime.h>

#define NS 7
#define NA 131072
#define AEVD 1008
#define KP1 1024
#define N1 256
#define N2 192
#define N3 160

typedef __attribute__((ext_vector_type(8))) short short8;
typedef __attribute__((ext_vector_type(8))) unsigned short ushortx8;
typedef __attribute__((ext_vector_type(4))) float f32x4;
typedef __attribute__((ext_vector_type(4))) float fvec4;
typedef unsigned short u16;

__device__ __forceinline__ u16 f2bf(float f) {
  unsigned u = __builtin_bit_cast(unsigned, f);
  u += 0x7fffu + ((u >> 16) & 1u);
  return (u16)(u >> 16);
}
__device__ __forceinline__ float bf2f(u16 h) {
  return __builtin_bit_cast(float, ((unsigned)h) << 16);
}
__device__ __forceinline__ float celu_f(float x) {
  return x > 0.f ? x : 0.1f * (__expf(x * 10.f) - 1.f);
}
__device__ __forceinline__ void pack8(fvec4 a, fvec4 b, ushortx8* dst) {
  ushortx8 p;
  p[0] = f2bf(a.x); p[1] = f2bf(a.y); p[2] = f2bf(a.z); p[3] = f2bf(a.w);
  p[4] = f2bf(b.x); p[5] = f2bf(b.y); p[6] = f2bf(b.z); p[7] = f2bf(b.w);
  *dst = p;
}
__device__ __forceinline__ fvec4 ld_aev(const float* row, int k) {
  if (k < AEVD) return __builtin_nontemporal_load((const fvec4*)(row + k));
  fvec4 z = {0.f, 0.f, 0.f, 0.f};
  return z;
}

// ---------------- bucketing ----------------
__global__ void count_kernel(const int* __restrict__ species, int* __restrict__ counts) {
  __shared__ int h[NS];
  if (threadIdx.x < NS) h[threadIdx.x] = 0;
  __syncthreads();
  int i = blockIdx.x * blockDim.x + threadIdx.x;
  if (i < NA) atomicAdd(&h[species[i]], 1);
  __syncthreads();
  if (threadIdx.x < NS) atomicAdd(&counts[threadIdx.x], h[threadIdx.x]);
}

__global__ void scan_kernel(const int* __restrict__ counts, int* __restrict__ offsets,
                            int* __restrict__ cursors, int* __restrict__ blockStart) {
  int off = 0, bs = 0;
  for (int e = 0; e < NS; ++e) {
    offsets[e] = off; cursors[e] = off; blockStart[e] = bs;
    off += counts[e];
    bs += (counts[e] + 63) >> 6;
  }
  offsets[NS] = off; blockStart[NS] = bs;
}

__global__ void scatter_kernel(const int* __restrict__ species, int* __restrict__ cursors,
                               int* __restrict__ idx) {
  __shared__ int h[NS], lb[NS];
  if (threadIdx.x < NS) h[threadIdx.x] = 0;
  __syncthreads();
  int i = blockIdx.x * blockDim.x + threadIdx.x;
  int s = species[i];
  int lpos = atomicAdd(&h[s], 1);
  __syncthreads();
  if (threadIdx.x < NS) lb[threadIdx.x] = atomicAdd(&cursors[threadIdx.x], h[threadIdx.x]);
  __syncthreads();
  idx[lb[s] + lpos] = i;
}

// ---------------- weight convert: dst[e][n][kp] = bf16(src[e][k][n]), zero pad k>=K ----------------
__global__ void convert_w(const float* __restrict__ src, u16* __restrict__ dst,
                          int K, int N, int KP) {
  long total = (long)NS * N * KP;
  for (long i = (long)blockIdx.x * blockDim.x + threadIdx.x; i < total;
       i += (long)gridDim.x * blockDim.x) {
    int kp = (int)(i % KP);
    long t2 = i / KP;
    int n = (int)(t2 % N);
    int e = (int)(t2 / N);
    float v = (kp < K) ? src[((long)e * K + kp) * N + n] : 0.f;
    dst[i] = f2bf(v);
  }
}

// ---------------- fused MLP ----------------
#define H1P 264
#define H2P 200
#define H3P 168

__global__ __launch_bounds__(256, 2) void ani_fused(
    const int* __restrict__ idx, const int* __restrict__ counts,
    const int* __restrict__ offsets, const int* __restrict__ blockStart,
    const float* __restrict__ aev,
    const u16* __restrict__ W1t, const float* __restrict__ b1,
    const u16* __restrict__ W2t, const float* __restrict__ b2,
    const u16* __restrict__ W3t, const float* __restrict__ b3,
    const u16* __restrict__ Wht, const float* __restrict__ bh,
    float* __restrict__ out) {
  __shared__ __align__(16) u16 AB[2][64 * 72];   // A double-buffer, pitch 72
  __shared__ __align__(16) u16 H1[64 * H1P];     // h1; h3 aliases this
  __shared__ __align__(16) u16 H2[64 * H2P];     // h2
  u16* H3 = H1;

  int bid = blockIdx.x;
  if (bid >= blockStart[NS]) return;
  int e = 0;
#pragma unroll
  for (int s = 1; s < NS; ++s)
    if (bid >= blockStart[s]) e = s;
  int t = bid - blockStart[e];
  int base = offsets[e] + (t << 6);
  int mcount = counts[e] - (t << 6);
  if (mcount > 64) mcount = 64;

  int tid = threadIdx.x;
  int lane = tid & 63;
  int w = tid >> 6;       // wave 0..3
  int lr = lane & 15;
  int kg = lane >> 4;

  // A staging: thread -> (row, 16-float chunk)
  int arow = tid >> 2;
  int aks = (tid & 3) << 4;
  int rrow = arow < mcount ? arow : (mcount - 1);
  const float* aevRow = aev + (size_t)idx[base + rrow] * AEVD;

  // ---------- prologue: stage A chunk k0=0 ----------
  {
    fvec4 v0 = ld_aev(aevRow, aks);
    fvec4 v1 = ld_aev(aevRow, aks + 4);
    fvec4 v2 = ld_aev(aevRow, aks + 8);
    fvec4 v3 = ld_aev(aevRow, aks + 12);
    pack8(v0, v1, (ushortx8*)&AB[0][arow * 72 + aks]);
    pack8(v2, v3, (ushortx8*)&AB[0][arow * 72 + aks + 8]);
  }
  __syncthreads();

  // ---------- layer 1: [64 x 1024] @ [1024 x 256], BK=64, A dbuf, B global->reg ----------
  f32x4 acc[4][4] = {};
  const u16* Wb1 = W1t + ((size_t)e * N1 + (w * 64 + lr)) * KP1 + kg * 8;

  for (int k0 = 0; k0 < KP1; k0 += 64) {
    int p = (k0 >> 6) & 1;
    bool have = (k0 + 64) < KP1;
    fvec4 v0, v1, v2, v3;
    if (have) {
      int kb = k0 + 64 + aks;
      v0 = ld_aev(aevRow, kb);
      v1 = ld_aev(aevRow, kb + 4);
      v2 = ld_aev(aevRow, kb + 8);
      v3 = ld_aev(aevRow, kb + 12);
    }
    short8 bfr[2][4];
#pragma unroll
    for (int kk = 0; kk < 2; ++kk)
#pragma unroll
      for (int ni = 0; ni < 4; ++ni)
        bfr[kk][ni] = *(const short8*)(Wb1 + (size_t)ni * 16 * KP1 + k0 + kk * 32);
    short8 af[2][4];
#pragma unroll
    for (int kk = 0; kk < 2; ++kk)
#pragma unroll
      for (int mi = 0; mi < 4; ++mi)
        af[kk][mi] = *(const short8*)&AB[p][(mi * 16 + lr) * 72 + kk * 32 + kg * 8];
#pragma unroll
    for (int kk = 0; kk < 2; ++kk)
#pragma unroll
      for (int ni = 0; ni < 4; ++ni)
#pragma unroll
        for (int mi = 0; mi < 4; ++mi)
          acc[mi][ni] = __builtin_amdgcn_mfma_f32_16x16x32_bf16(af[kk][mi], bfr[kk][ni], acc[mi][ni], 0, 0, 0);
    if (have) {
      pack8(v0, v1, (ushortx8*)&AB[p ^ 1][arow * 72 + aks]);
      pack8(v2, v3, (ushortx8*)&AB[p ^ 1][arow * 72 + aks + 8]);
    }
    __syncthreads();
  }

  // epilogue 1 -> H1
#pragma unroll
  for (int ni = 0; ni < 4; ++ni) {
    int col = w * 64 + ni * 16 + lr;
    float bias = b1[e * N1 + col];
#pragma unroll
    for (int mi = 0; mi < 4; ++mi)
#pragma unroll
      for (int r = 0; r < 4; ++r)
        H1[(mi * 16 + kg * 4 + r) * H1P + col] = f2bf(celu_f(acc[mi][ni][r] + bias));
  }
  __syncthreads();

  // ---------- layer 2: [64 x 256] @ [256 x 192], no barriers in loop ----------
  int mr2 = (w & 1) * 32;
  int nc2 = (w >> 1) * 96;
  f32x4 acc2[2][6] = {};
  const u16* Wb2 = W2t + ((size_t)e * N2 + (nc2 + lr)) * N1 + kg * 8;
#pragma unroll 4
  for (int k0 = 0; k0 < N1; k0 += 32) {
    short8 a0 = *(const short8*)&H1[(mr2 + lr) * H1P + k0 + kg * 8];
    short8 a1 = *(const short8*)&H1[(mr2 + 16 + lr) * H1P + k0 + kg * 8];
#pragma unroll
    for (int ni = 0; ni < 6; ++ni) {
      short8 b = *(const short8*)(Wb2 + (size_t)ni * 16 * N1 + k0);
      acc2[0][ni] = __builtin_amdgcn_mfma_f32_16x16x32_bf16(a0, b, acc2[0][ni], 0, 0, 0);
      acc2[1][ni] = __builtin_amdgcn_mfma_f32_16x16x32_bf16(a1, b, acc2[1][ni], 0, 0, 0);
    }
  }
  // epilogue 2 -> H2
#pragma unroll
  for (int ni = 0; ni < 6; ++ni) {
    int col = nc2 + ni * 16 + lr;
    float bias = b2[e * N2 + col];
#pragma unroll
    for (int mi = 0; mi < 2; ++mi)
#pragma unroll
      for (int r = 0; r < 4; ++r)
        H2[(mr2 + mi * 16 + kg * 4 + r) * H2P + col] = f2bf(celu_f(acc2[mi][ni][r] + bias));
  }
  __syncthreads();

  // ---------- layer 3: [64 x 192] @ [192 x 160], no barriers in loop ----------
  int mr3 = (w & 1) * 32;
  int nc3 = (w >> 1) * 80;
  f32x4 acc3[2][5] = {};
  const u16* Wb3 = W3t + ((size_t)e * N3 + (nc3 + lr)) * N2 + kg * 8;
#pragma unroll 3
  for (int k0 = 0; k0 < N2; k0 += 32) {
    short8 a0 = *(const short8*)&H2[(mr3 + lr) * H2P + k0 + kg * 8];
    short8 a1 = *(const short8*)&H2[(mr3 + 16 + lr) * H2P + k0 + kg * 8];
#pragma unroll
    for (int ni = 0; ni < 5; ++ni) {
      short8 b = *(const short8*)(Wb3 + (size_t)ni * 16 * N2 + k0);
      acc3[0][ni] = __builtin_amdgcn_mfma_f32_16x16x32_bf16(a0, b, acc3[0][ni], 0, 0, 0);
      acc3[1][ni] = __builtin_amdgcn_mfma_f32_16x16x32_bf16(a1, b, acc3[1][ni], 0, 0, 0);
    }
  }
  // epilogue 3 -> H3 (aliases H1; safe: all h1 reads ended at the barrier above)
#pragma unroll
  for (int ni = 0; ni < 5; ++ni) {
    int col = nc3 + ni * 16 + lr;
    float bias = b3[e * N3 + col];
#pragma unroll
    for (int mi = 0; mi < 2; ++mi)
#pragma unroll
      for (int r = 0; r < 4; ++r)
        H3[(mr3 + mi * 16 + kg * 4 + r) * H3P + col] = f2bf(celu_f(acc3[mi][ni][r] + bias));
  }
  __syncthreads();

  // ---------- head: [64 x 160] @ [160 x 2], split-K over thread pairs ----------
  {
    int r = tid >> 2;
    int o = (tid >> 1) & 1;
    int kh = tid & 1;
    float s = 0.f;
    const u16* wr = Wht + ((size_t)e * 2 + o) * N3 + kh * 80;
    const u16* hr = &H3[r * H3P + kh * 80];
#pragma unroll
    for (int c = 0; c < 10; ++c) {
      ushortx8 hv = *(const ushortx8*)&hr[c * 8];
      ushortx8 wv = *(const ushortx8*)&wr[c * 8];
#pragma unroll
      for (int j = 0; j < 8; ++j) s += bf2f(hv[j]) * bf2f(wv[j]);
    }
    s += __shfl_xor(s, 1);
    if (kh == 0 && r < mcount) out[(size_t)idx[base + r] * 2 + o] = s + bh[e * 2 + o];
  }
}

extern "C" void kernel_launch(void* const* d_in, const int* in_sizes, int n_in,
                              void* d_out, int out_size, void* d_ws, size_t ws_size,
                              hipStream_t stream) {
  const int* species = (const int*)d_in[0];
  const float* aev = (const float*)d_in[1];
  const float* W1 = (const float*)d_in[2];
  const float* b1 = (const float*)d_in[3];
  const float* W2 = (const float*)d_in[4];
  const float* b2 = (const float*)d_in[5];
  const float* W3 = (const float*)d_in[6];
  const float* b3 = (const float*)d_in[7];
  const float* Wh = (const float*)d_in[8];
  const float* bh = (const float*)d_in[9];
  float* out = (float*)d_out;

  char* p = (char*)d_ws;
  int* counts = (int*)p; p += 32;
  int* offsets = (int*)p; p += 32;
  int* cursors = (int*)p; p += 32;
  int* blockStart = (int*)p; p += 32;
  int* idx = (int*)p; p += (size_t)NA * 4;
  u16* W1t = (u16*)p; p += (size_t)NS * N1 * KP1 * 2;
  u16* W2t = (u16*)p; p += (size_t)NS * N2 * N1 * 2;
  u16* W3t = (u16*)p; p += (size_t)NS * N3 * N2 * 2;
  u16* Wht = (u16*)p; p += (size_t)NS * 2 * N3 * 2;

  (void)hipMemsetAsync(counts, 0, 32, stream);
  count_kernel<<<NA / 256, 256, 0, stream>>>(species, counts);
  scan_kernel<<<1, 1, 0, stream>>>(counts, offsets, cursors, blockStart);
  scatter_kernel<<<NA / 256, 256, 0, stream>>>(species, cursors, idx);

  convert_w<<<2048, 256, 0, stream>>>(W1, W1t, AEVD, N1, KP1);
  convert_w<<<1024, 256, 0, stream>>>(W2, W2t, N1, N2, N1);
  convert_w<<<512, 256, 0, stream>>>(W3, W3t, N2, N3, N2);
  convert_w<<<16, 256, 0, stream>>>(Wh, Wht, N3, 2, N3);

  int maxBlocks = (NA >> 6) + NS;
  ani_fused<<<maxBlocks, 256, 0, stream>>>(idx, counts, offsets, blockStart, aev,
                                           W1t, b1, W2t, b2, W3t, b3, Wht, bh, out);
}

// Round 4
// 328.528 us; speedup vs baseline: 1.4324x; 1.4324x over previous
//
#include <hip/hip_runtime.h>

#define NS 7
#define NA 131072
#define AEVD 1008
#define KP1 1024
#define N1 256
#define N2 192
#define N3 160

typedef __attribute__((ext_vector_type(8))) short short8;
typedef __attribute__((ext_vector_type(8))) unsigned short ushortx8;
typedef __attribute__((ext_vector_type(4))) float f32x4;
typedef __attribute__((ext_vector_type(4))) float fvec4;
typedef unsigned short u16;

// LDS-only barrier: waits ds ops, does NOT drain vmcnt -> register prefetches
// survive across the barrier (T4). Single asm => nothing can schedule between
// the wait and the barrier; "memory" clobber pins all IR memory ops.
#define BAR() asm volatile("s_waitcnt lgkmcnt(0)\ns_barrier" ::: "memory")

__device__ __forceinline__ u16 f2bf(float f) {
  unsigned u = __builtin_bit_cast(unsigned, f);
  u += 0x7fffu + ((u >> 16) & 1u);
  return (u16)(u >> 16);
}
__device__ __forceinline__ float bf2f(u16 h) {
  return __builtin_bit_cast(float, ((unsigned)h) << 16);
}
__device__ __forceinline__ float celu_f(float x) {
  return x > 0.f ? x : 0.1f * (__expf(x * 10.f) - 1.f);
}
__device__ __forceinline__ void pack8(fvec4 a, fvec4 b, ushortx8* dst) {
  ushortx8 p;
  p[0] = f2bf(a.x); p[1] = f2bf(a.y); p[2] = f2bf(a.z); p[3] = f2bf(a.w);
  p[4] = f2bf(b.x); p[5] = f2bf(b.y); p[6] = f2bf(b.z); p[7] = f2bf(b.w);
  *dst = p;
}
__device__ __forceinline__ fvec4 ld_aev(const float* row, int k) {
  if (k < AEVD) return *(const fvec4*)(row + k);
  fvec4 z = {0.f, 0.f, 0.f, 0.f};
  return z;
}

// ---------------- bucketing ----------------
__global__ void count_kernel(const int* __restrict__ species, int* __restrict__ counts) {
  __shared__ int h[NS];
  if (threadIdx.x < NS) h[threadIdx.x] = 0;
  __syncthreads();
  int i = blockIdx.x * blockDim.x + threadIdx.x;
  if (i < NA) atomicAdd(&h[species[i]], 1);
  __syncthreads();
  if (threadIdx.x < NS) atomicAdd(&counts[threadIdx.x], h[threadIdx.x]);
}

__global__ void scan_kernel(const int* __restrict__ counts, int* __restrict__ offsets,
                            int* __restrict__ cursors, int* __restrict__ blockStart) {
  int off = 0, bs = 0;
  for (int e = 0; e < NS; ++e) {
    offsets[e] = off; cursors[e] = off; blockStart[e] = bs;
    off += counts[e];
    bs += (counts[e] + 63) >> 6;
  }
  offsets[NS] = off; blockStart[NS] = bs;
}

__global__ void scatter_kernel(const int* __restrict__ species, int* __restrict__ cursors,
                               int* __restrict__ idx) {
  __shared__ int h[NS], lb[NS];
  if (threadIdx.x < NS) h[threadIdx.x] = 0;
  __syncthreads();
  int i = blockIdx.x * blockDim.x + threadIdx.x;
  int s = species[i];
  int lpos = atomicAdd(&h[s], 1);
  __syncthreads();
  if (threadIdx.x < NS) lb[threadIdx.x] = atomicAdd(&cursors[threadIdx.x], h[threadIdx.x]);
  __syncthreads();
  idx[lb[s] + lpos] = i;
}

// ---------------- weight convert: dst[e][n][kp] = bf16(src[e][k][n]), zero pad k>=K ----------------
__global__ void convert_w(const float* __restrict__ src, u16* __restrict__ dst,
                          int K, int N, int KP) {
  long total = (long)NS * N * KP;
  for (long i = (long)blockIdx.x * blockDim.x + threadIdx.x; i < total;
       i += (long)gridDim.x * blockDim.x) {
    int kp = (int)(i % KP);
    long t2 = i / KP;
    int n = (int)(t2 % N);
    int e = (int)(t2 / N);
    float v = (kp < K) ? src[((long)e * K + kp) * N + n] : 0.f;
    dst[i] = f2bf(v);
  }
}

// ---------------- fused MLP ----------------
#define H1P 264
#define H2P 200
#define H3P 168

__global__ __launch_bounds__(256, 2) void ani_fused(
    const int* __restrict__ idx, const int* __restrict__ counts,
    const int* __restrict__ offsets, const int* __restrict__ blockStart,
    const float* __restrict__ aev,
    const u16* __restrict__ W1t, const float* __restrict__ b1,
    const u16* __restrict__ W2t, const float* __restrict__ b2,
    const u16* __restrict__ W3t, const float* __restrict__ b3,
    const u16* __restrict__ Wht, const float* __restrict__ bh,
    float* __restrict__ out) {
  __shared__ __align__(16) u16 AB[2][64 * 72];
  __shared__ __align__(16) u16 H1[64 * H1P];
  __shared__ __align__(16) u16 H2[64 * H2P];
  u16* H3 = H1;

  int bid = blockIdx.x;
  if (bid >= blockStart[NS]) return;
  int e = 0;
#pragma unroll
  for (int s = 1; s < NS; ++s)
    if (bid >= blockStart[s]) e = s;
  int t = bid - blockStart[e];
  int base = offsets[e] + (t << 6);
  int mcount = counts[e] - (t << 6);
  if (mcount > 64) mcount = 64;

  int tid = threadIdx.x;
  int lane = tid & 63;
  int w = tid >> 6;
  int lr = lane & 15;
  int kg = lane >> 4;

  int arow = tid >> 2;
  int aks = (tid & 3) << 4;
  int rrow = arow < mcount ? arow : (mcount - 1);
  const float* aevRow = aev + (size_t)idx[base + rrow] * AEVD;

  const u16* Wb1 = W1t + ((size_t)e * N1 + (w * 64 + lr)) * KP1 + kg * 8;

  auto loadA = [&](int chunk, fvec4 (&v)[4]) {
    int kb = chunk * 64 + aks;
    v[0] = ld_aev(aevRow, kb);
    v[1] = ld_aev(aevRow, kb + 4);
    v[2] = ld_aev(aevRow, kb + 8);
    v[3] = ld_aev(aevRow, kb + 12);
  };
  auto loadB1 = [&](int chunk, short8 (&b)[2][4]) {
#pragma unroll
    for (int kk = 0; kk < 2; ++kk)
#pragma unroll
      for (int ni = 0; ni < 4; ++ni)
        b[kk][ni] = *(const short8*)(Wb1 + (size_t)ni * 16 * KP1 + chunk * 64 + kk * 32);
  };

  f32x4 acc[4][4] = {};

  auto iter1 = [&](int c, int p, short8 (&bfr)[2][4], fvec4 (&pre)[4]) {
    short8 af[2][4];
#pragma unroll
    for (int kk = 0; kk < 2; ++kk)
#pragma unroll
      for (int mi = 0; mi < 4; ++mi)
        af[kk][mi] = *(const short8*)&AB[p][(mi * 16 + lr) * 72 + kk * 32 + kg * 8];
    if (c + 1 < 16) {  // pack chunk c+1 (loaded 2 iters ago) into AB[p^1]
      pack8(pre[0], pre[1], (ushortx8*)&AB[p ^ 1][arow * 72 + aks]);
      pack8(pre[2], pre[3], (ushortx8*)&AB[p ^ 1][arow * 72 + aks + 8]);
    }
    if (c + 3 < 16) loadA(c + 3, pre);  // refill A prefetch (2 ahead of pack)
#pragma unroll
    for (int kk = 0; kk < 2; ++kk)
#pragma unroll
      for (int ni = 0; ni < 4; ++ni)
#pragma unroll
        for (int mi = 0; mi < 4; ++mi)
          acc[mi][ni] = __builtin_amdgcn_mfma_f32_16x16x32_bf16(af[kk][mi], bfr[kk][ni], acc[mi][ni], 0, 0, 0);
    if (c + 2 < 16) loadB1(c + 2, bfr);  // refill B prefetch (2 ahead)
    BAR();
  };

  // ---------- layer 1 prologue ----------
  {
    fvec4 t0[4];
    loadA(0, t0);
    pack8(t0[0], t0[1], (ushortx8*)&AB[0][arow * 72 + aks]);
    pack8(t0[2], t0[3], (ushortx8*)&AB[0][arow * 72 + aks + 8]);
  }
  fvec4 pA[4], pB[4];
  loadA(1, pA);
  loadA(2, pB);
  short8 bA[2][4], bB[2][4];
  loadB1(0, bA);
  loadB1(1, bB);
  BAR();

  for (int c = 0; c < 16; c += 2) {
    iter1(c, 0, bA, pA);
    iter1(c + 1, 1, bB, pB);
  }

  // ---------- layer 2 B prefetch (hoisted above epilogue-1 barrier) ----------
  int mr2 = (w & 1) * 32;
  int nc2 = (w >> 1) * 96;
  const u16* Wb2 = W2t + ((size_t)e * N2 + (nc2 + lr)) * N1 + kg * 8;
  auto loadB2 = [&](int k0, short8 (&b)[6]) {
#pragma unroll
    for (int ni = 0; ni < 6; ++ni)
      b[ni] = *(const short8*)(Wb2 + (size_t)ni * 16 * N1 + k0);
  };
  short8 c2A[6], c2B[6], c2C[6], c2D[6];
  loadB2(0, c2A); loadB2(32, c2B); loadB2(64, c2C); loadB2(96, c2D);

  // epilogue 1 -> H1
#pragma unroll
  for (int ni = 0; ni < 4; ++ni) {
    int col = w * 64 + ni * 16 + lr;
    float bias = b1[e * N1 + col];
#pragma unroll
    for (int mi = 0; mi < 4; ++mi)
#pragma unroll
      for (int r = 0; r < 4; ++r)
        H1[(mi * 16 + kg * 4 + r) * H1P + col] = f2bf(celu_f(acc[mi][ni][r] + bias));
  }
  BAR();

  // ---------- layer 2: 8 steps fully unrolled, 4-deep B ring ----------
  f32x4 acc2[2][6] = {};
  auto mm2 = [&](int k0, short8 (&b)[6]) {
    short8 a0 = *(const short8*)&H1[(mr2 + lr) * H1P + k0 + kg * 8];
    short8 a1 = *(const short8*)&H1[(mr2 + 16 + lr) * H1P + k0 + kg * 8];
#pragma unroll
    for (int ni = 0; ni < 6; ++ni) {
      acc2[0][ni] = __builtin_amdgcn_mfma_f32_16x16x32_bf16(a0, b[ni], acc2[0][ni], 0, 0, 0);
      acc2[1][ni] = __builtin_amdgcn_mfma_f32_16x16x32_bf16(a1, b[ni], acc2[1][ni], 0, 0, 0);
    }
  };
  mm2(0, c2A);   loadB2(128, c2A);
  mm2(32, c2B);  loadB2(160, c2B);
  mm2(64, c2C);  loadB2(192, c2C);
  mm2(96, c2D);  loadB2(224, c2D);
  mm2(128, c2A);
  mm2(160, c2B);
  mm2(192, c2C);
  mm2(224, c2D);

  // ---------- layer 3 B prefetch (hoisted above epilogue-2 barrier) ----------
  int mr3 = (w & 1) * 32;
  int nc3 = (w >> 1) * 80;
  const u16* Wb3 = W3t + ((size_t)e * N3 + (nc3 + lr)) * N2 + kg * 8;
  auto loadB3 = [&](int k0, short8 (&b)[5]) {
#pragma unroll
    for (int ni = 0; ni < 5; ++ni)
      b[ni] = *(const short8*)(Wb3 + (size_t)ni * 16 * N2 + k0);
  };
  short8 c3A[5], c3B[5], c3C[5];
  loadB3(0, c3A); loadB3(32, c3B); loadB3(64, c3C);

  // epilogue 2 -> H2
#pragma unroll
  for (int ni = 0; ni < 6; ++ni) {
    int col = nc2 + ni * 16 + lr;
    float bias = b2[e * N2 + col];
#pragma unroll
    for (int mi = 0; mi < 2; ++mi)
#pragma unroll
      for (int r = 0; r < 4; ++r)
        H2[(mr2 + mi * 16 + kg * 4 + r) * H2P + col] = f2bf(celu_f(acc2[mi][ni][r] + bias));
  }
  BAR();

  // ---------- layer 3: 6 steps fully unrolled, 3-deep B ring ----------
  f32x4 acc3[2][5] = {};
  auto mm3 = [&](int k0, short8 (&b)[5]) {
    short8 a0 = *(const short8*)&H2[(mr3 + lr) * H2P + k0 + kg * 8];
    short8 a1 = *(const short8*)&H2[(mr3 + 16 + lr) * H2P + k0 + kg * 8];
#pragma unroll
    for (int ni = 0; ni < 5; ++ni) {
      acc3[0][ni] = __builtin_amdgcn_mfma_f32_16x16x32_bf16(a0, b[ni], acc3[0][ni], 0, 0, 0);
      acc3[1][ni] = __builtin_amdgcn_mfma_f32_16x16x32_bf16(a1, b[ni], acc3[1][ni], 0, 0, 0);
    }
  };
  mm3(0, c3A);   loadB3(96, c3A);
  mm3(32, c3B);  loadB3(128, c3B);
  mm3(64, c3C);  loadB3(160, c3C);
  mm3(96, c3A);
  mm3(128, c3B);
  mm3(160, c3C);

  // ---------- head weights prefetch (hoisted above epilogue-3 barrier) ----------
  int hr_ = tid >> 2;
  int ho = (tid >> 1) & 1;
  int kh = tid & 1;
  const u16* wr = Wht + ((size_t)e * 2 + ho) * N3 + kh * 80;
  ushortx8 wvv[10];
#pragma unroll
  for (int c = 0; c < 10; ++c) wvv[c] = *(const ushortx8*)&wr[c * 8];

  // epilogue 3 -> H3 (aliases H1)
#pragma unroll
  for (int ni = 0; ni < 5; ++ni) {
    int col = nc3 + ni * 16 + lr;
    float bias = b3[e * N3 + col];
#pragma unroll
    for (int mi = 0; mi < 2; ++mi)
#pragma unroll
      for (int r = 0; r < 4; ++r)
        H3[(mr3 + mi * 16 + kg * 4 + r) * H3P + col] = f2bf(celu_f(acc3[mi][ni][r] + bias));
  }
  BAR();

  // ---------- head ----------
  {
    float s = 0.f;
    const u16* hrow = &H3[hr_ * H3P + kh * 80];
#pragma unroll
    for (int c = 0; c < 10; ++c) {
      ushortx8 hv = *(const ushortx8*)&hrow[c * 8];
#pragma unroll
      for (int j = 0; j < 8; ++j) s += bf2f(hv[j]) * bf2f(wvv[c][j]);
    }
    s += __shfl_xor(s, 1);
    if (kh == 0 && hr_ < mcount) out[(size_t)idx[base + hr_] * 2 + ho] = s + bh[e * 2 + ho];
  }
}

extern "C" void kernel_launch(void* const* d_in, const int* in_sizes, int n_in,
                              void* d_out, int out_size, void* d_ws, size_t ws_size,
                              hipStream_t stream) {
  const int* species = (const int*)d_in[0];
  const float* aev = (const float*)d_in[1];
  const float* W1 = (const float*)d_in[2];
  const float* b1 = (const float*)d_in[3];
  const float* W2 = (const float*)d_in[4];
  const float* b2 = (const float*)d_in[5];
  const float* W3 = (const float*)d_in[6];
  const float* b3 = (const float*)d_in[7];
  const float* Wh = (const float*)d_in[8];
  const float* bh = (const float*)d_in[9];
  float* out = (float*)d_out;

  char* p = (char*)d_ws;
  int* counts = (int*)p; p += 32;
  int* offsets = (int*)p; p += 32;
  int* cursors = (int*)p; p += 32;
  int* blockStart = (int*)p; p += 32;
  int* idx = (int*)p; p += (size_t)NA * 4;
  u16* W1t = (u16*)p; p += (size_t)NS * N1 * KP1 * 2;
  u16* W2t = (u16*)p; p += (size_t)NS * N2 * N1 * 2;
  u16* W3t = (u16*)p; p += (size_t)NS * N3 * N2 * 2;
  u16* Wht = (u16*)p; p += (size_t)NS * 2 * N3 * 2;

  (void)hipMemsetAsync(counts, 0, 32, stream);
  count_kernel<<<NA / 256, 256, 0, stream>>>(species, counts);
  scan_kernel<<<1, 1, 0, stream>>>(counts, offsets, cursors, blockStart);
  scatter_kernel<<<NA / 256, 256, 0, stream>>>(species, cursors, idx);

  convert_w<<<2048, 256, 0, stream>>>(W1, W1t, AEVD, N1, KP1);
  convert_w<<<1024, 256, 0, stream>>>(W2, W2t, N1, N2, N1);
  convert_w<<<512, 256, 0, stream>>>(W3, W3t, N2, N3, N2);
  convert_w<<<16, 256, 0, stream>>>(Wh, Wht, N3, 2, N3);

  int maxBlocks = (NA >> 6) + NS;
  ani_fused<<<maxBlocks, 256, 0, stream>>>(idx, counts, offsets, blockStart, aev,
                                           W1t, b1, W2t, b2, W3t, b3, Wht, bh, out);
}